// Round 12
// baseline (190.751 us; speedup 1.0000x reference)
//
#include <hip/hip_runtime.h>
#include <hip/hip_bf16.h>

#define HDIM 128

typedef short bf16x8 __attribute__((ext_vector_type(8)));
typedef short bf16x4 __attribute__((ext_vector_type(4)));
typedef unsigned short u16x8 __attribute__((ext_vector_type(8)));
typedef float f32x4 __attribute__((ext_vector_type(4)));

__device__ __forceinline__ short f2bf(float f) {
    __hip_bfloat16 h = __float2bfloat16(f);
    union { __hip_bfloat16 h; short s; } c; c.h = h; return c.s;
}
__device__ __forceinline__ float bf2f(unsigned short h) {
    union { unsigned u; float f; } c; c.u = ((unsigned)h) << 16; return c.f;
}
__device__ __forceinline__ bf16x8 pack8(float4 a, float4 b) {
    bf16x8 r;
    r[0] = f2bf(a.x); r[1] = f2bf(a.y); r[2] = f2bf(a.z); r[3] = f2bf(a.w);
    r[4] = f2bf(b.x); r[5] = f2bf(b.y); r[6] = f2bf(b.z); r[7] = f2bf(b.w);
    return r;
}

// lgkm-only barrier: orders LDS ops across waves WITHOUT draining vmcnt.
__device__ __forceinline__ void barrier_lds() {
    asm volatile("s_waitcnt lgkmcnt(0)" ::: "memory");
    __builtin_amdgcn_s_barrier();
    __builtin_amdgcn_sched_barrier(0);
}

// ---- phase 1: r8's 1-barrier software pipeline + r10's FRAGMENT-LINEAR LDS.
// All LDS tiles stored as [frag(gp*4+kt)][lane][8 shorts]: every DS access is
// lane-linear (lane i -> base + i*16B) = conflict-free (r10 evidence: 3e6
// conflicts vs r9's 1.1e7 with row-major+XOR reads).
// Fragment (gp,kt), slot l holds X[gp*16+(l&15)][kt*32+(l>>4)*8+i].
// Pipeline (r8 schedule): iter i does A:h1,h2(T_i), B:g1(T_{i-1}),
// stores h2(T_{i-1})/g1(T_{i-2}), z-prefetch T_{i+1} in registers, ONE barrier.
__global__ __launch_bounds__(512, 4)
void node_phase(const float* __restrict__ z,
                const float* __restrict__ w1, const float* __restrict__ b1,
                const float* __restrict__ w2, const float* __restrict__ b2,
                const float* __restrict__ wb,
                unsigned short* __restrict__ g1, unsigned short* __restrict__ h2o,
                int N)
{
    __shared__ short zbb[2][4096];   // 8 KB/side z tile, fragment-linear
    __shared__ short h1x[2][4096];   // h1 exchange
    __shared__ short h2x[2][4096];   // h2 store staging
    __shared__ short g1x[2][4096];   // g1 store staging

    const int t = threadIdx.x;
    const int lane = t & 63, wid = t >> 6;
    const int l15 = lane & 15, kgrp = lane >> 4;
    const int feat = wid * 16 + l15;

    // persistent weight A-fragments (each matrix read exactly once per block)
    bf16x8 w1f[4], w2f[4], wbf[4];
    {
        const float* w1r = w1 + (size_t)feat * HDIM;
        const float* w2r = w2 + (size_t)feat * HDIM;
#pragma unroll
        for (int kt = 0; kt < 4; ++kt) {
            int k0 = kt * 32 + kgrp * 8;
            w1f[kt] = pack8(*(const float4*)(w1r + k0), *(const float4*)(w1r + k0 + 4));
            w2f[kt] = pack8(*(const float4*)(w2r + k0), *(const float4*)(w2r + k0 + 4));
            bf16x8 r;  // A[i][k=n] = wb[n][feat] column gather (once per block)
#pragma unroll
            for (int i = 0; i < 8; ++i) r[i] = f2bf(wb[(size_t)(k0 + i) * HDIM + feat]);
            wbf[kt] = r;
        }
    }
    f32x4 bias1, bias2;
#pragma unroll
    for (int r = 0; r < 4; ++r) {
        bias1[r] = b1[wid * 16 + kgrp * 4 + r];
        bias2[r] = b2[wid * 16 + kgrp * 4 + r];
    }

    // staging/store bijection (r10): thread t owns fragment slot t ->
    //   node row = ((t>>8)<<4)|(t&15), feature col = ((t>>6)&3)*32+((t>>4)&3)*8
    const int zrow = ((t >> 8) << 4) | (t & 15);
    const int zcol = ((t >> 6) & 3) * 32 + ((t >> 4) & 3) * 8;

    // phase-A/B D-write decomposition (r10): feature f = wid*16+kgrp*4+r ->
    //   frag kt'=wid>>1, kgrp'=((wid&1)<<1)|(kgrp>>1), elem base (kgrp&1)*4
    const int dbase = ((wid >> 1) * 64 + ((((wid & 1) << 1) | (kgrp >> 1)) * 16)) * 8
                    + ((kgrp & 1) << 2);   // + gp*2048 + l15*8 at use site

    const int ntiles = (N + 31) >> 5;
    const int myTiles = (ntiles > (int)blockIdx.x)
                      ? ((ntiles - 1 - (int)blockIdx.x) / (int)gridDim.x + 1) : 0;
    const int nit = myTiles + 2;

    // prologue: stage tile T_0 into zbb[0]
    if (myTiles > 0) {
        int row = (int)blockIdx.x * 32 + zrow;
        int rc = row < N ? row : N - 1;
        const float* src = z + (size_t)rc * HDIM + zcol;
        *(bf16x8*)&zbb[0][t * 8] = pack8(*(const float4*)src, *(const float4*)(src + 4));
    }
    __syncthreads();

    for (int i = 0; i < nit; ++i) {
        const int cur = i & 1, prv = cur ^ 1;
        const int tvA = (int)blockIdx.x + i * (int)gridDim.x;
        const bool vA = (i < myTiles);
        const bool vB = (i >= 1) && (i - 1 < myTiles);
        const bool vG = (i >= 2) && (i - 2 < myTiles);
        const bool vP = (i + 1 < myTiles);

        // 1. issue z loads for T_{i+1} (consumed at step 6 -> full iter of cover)
        float4 zn0, zn1;
        if (vP) {
            int row = (tvA + (int)gridDim.x) * 32 + zrow;
            int rc = row < N ? row : N - 1;
            const float* src = z + (size_t)rc * HDIM + zcol;
            zn0 = *(const float4*)src;
            zn1 = *(const float4*)(src + 4);
        }
        // 2. g1 store for T_{i-2}: lane-linear LDS read, col decoded from slot
        if (vG) {
            int row = (tvA - 2 * (int)gridDim.x) * 32 + zrow;
            u16x8 vv = *(const u16x8*)&g1x[prv][t * 8];
            if (row < N) *(u16x8*)&g1[(size_t)row * HDIM + zcol] = vv;
        }
        // 3. h2 store for T_{i-1}
        if (vB) {
            int row = (tvA - (int)gridDim.x) * 32 + zrow;
            u16x8 vv = *(const u16x8*)&h2x[prv][t * 8];
            if (row < N) *(u16x8*)&h2o[(size_t)row * HDIM + zcol] = vv;
        }
        // 4. phase A: h1,h2 for T_i from zbb[cur] (lane-linear fragment reads)
        if (vA) {
#pragma unroll
            for (int gp = 0; gp < 2; ++gp) {
                bf16x8 zf[4];
#pragma unroll
                for (int kt = 0; kt < 4; ++kt)
                    zf[kt] = *(const bf16x8*)&zbb[cur][((gp * 4 + kt) * 64 + lane) * 8];
                f32x4 a1 = bias1, a3 = bias2;
#pragma unroll
                for (int kt = 0; kt < 4; ++kt) {
                    a1 = __builtin_amdgcn_mfma_f32_16x16x32_bf16(w1f[kt], zf[kt], a1, 0, 0, 0);
                    a3 = __builtin_amdgcn_mfma_f32_16x16x32_bf16(w2f[kt], zf[kt], a3, 0, 0, 0);
                }
                const int sidx = gp * 2048 + dbase + l15 * 8;
                bf16x4 h1v, h2v;
#pragma unroll
                for (int r = 0; r < 4; ++r) {
                    float x1 = a1[r] > 0.f ? a1[r] : 0.f;
                    float x2 = a3[r] > 0.f ? a3[r] : 0.f;
                    h1v[r] = f2bf(x1);
                    h2v[r] = f2bf(x2);
                }
                *(bf16x4*)&h1x[cur][sidx] = h1v;
                *(bf16x4*)&h2x[cur][sidx] = h2v;
            }
        }
        // 5. phase B: g1 for T_{i-1} from h1x[prv]
        if (vB) {
#pragma unroll
            for (int gp = 0; gp < 2; ++gp) {
                f32x4 ag = (f32x4){0.f, 0.f, 0.f, 0.f};
#pragma unroll
                for (int kt = 0; kt < 4; ++kt) {
                    bf16x8 bf = *(const bf16x8*)&h1x[prv][((gp * 4 + kt) * 64 + lane) * 8];
                    ag = __builtin_amdgcn_mfma_f32_16x16x32_bf16(wbf[kt], bf, ag, 0, 0, 0);
                }
                const int sidx = gp * 2048 + dbase + l15 * 8;
                bf16x4 gv;
#pragma unroll
                for (int r = 0; r < 4; ++r) gv[r] = f2bf(ag[r]);
                *(bf16x4*)&g1x[cur][sidx] = gv;
            }
        }
        // 6. write next z tile into zbb[prv] (vmcnt waits only past step-1 loads)
        if (vP) {
            *(bf16x8*)&zbb[prv][t * 8] = pack8(zn0, zn1);
        }
        // 7. ONE barrier seals zbb[prv], h1x/h2x/g1x[cur] for the next iteration
        barrier_lds();
    }
}

// ---- index dtype detection (parallel): int64 arcs have zero high words ---
__global__ void detect_idx64(const int* __restrict__ arcs, int* __restrict__ flag)
{
    int v = arcs[2 * threadIdx.x + 1];
    unsigned long long any = __ballot(v != 0);
    if (threadIdx.x == 0) *flag = (any == 0ull) ? 1 : 0;
}

// ---- phase 2: score[e] = dot(g1[u], h2[v]) + bb -------------------------
// 4 edges per 16-lane group: 8 independent 16B gathers in flight per thread.
__global__ __launch_bounds__(256, 8)
void edge_phase(const unsigned short* __restrict__ g1,
                const unsigned short* __restrict__ h2,
                const void* __restrict__ arcs,
                const int* __restrict__ flag,
                const float* __restrict__ bb,
                float* __restrict__ out, int E)
{
    const int t = threadIdx.x;
    const int sub = t & 15;
    const int grp = t >> 4;              // 16 groups/block, 4 edges each
    const bool is64 = (*flag != 0);
    const float bias = bb[0];

    for (int base = (int)blockIdx.x * 64; base < E; base += (int)gridDim.x * 64) {
        const int e0 = base + grp * 4;
        long long u[4], v[4];
#pragma unroll
        for (int j = 0; j < 4; ++j) {
            int ec = (e0 + j) < E ? (e0 + j) : (E - 1);
            if (is64) {
                const long long* a = (const long long*)arcs;
                u[j] = a[2 * (size_t)ec]; v[j] = a[2 * (size_t)ec + 1];
            } else {
                const int* a = (const int*)arcs;
                u[j] = a[2 * (size_t)ec]; v[j] = a[2 * (size_t)ec + 1];
            }
        }
        u16x8 av[4], bv[4];
#pragma unroll
        for (int j = 0; j < 4; ++j) {
            av[j] = *(const u16x8*)(g1 + (size_t)u[j] * HDIM + sub * 8);
            bv[j] = *(const u16x8*)(h2 + (size_t)v[j] * HDIM + sub * 8);
        }
#pragma unroll
        for (int j = 0; j < 4; ++j) {
            float s = 0.f;
#pragma unroll
            for (int i = 0; i < 8; ++i) s += bf2f(av[j][i]) * bf2f(bv[j][i]);
            s += __shfl_xor(s, 8, 16);
            s += __shfl_xor(s, 4, 16);
            s += __shfl_xor(s, 2, 16);
            s += __shfl_xor(s, 1, 16);
            if (sub == 0 && (e0 + j) < E) out[e0 + j] = s + bias;
        }
    }
}

extern "C" void kernel_launch(void* const* d_in, const int* in_sizes, int n_in,
                              void* d_out, int out_size, void* d_ws, size_t ws_size,
                              hipStream_t stream)
{
    const float* z  = (const float*)d_in[0];
    const float* w1 = (const float*)d_in[1];
    const float* b1 = (const float*)d_in[2];
    const float* w2 = (const float*)d_in[3];
    const float* b2 = (const float*)d_in[4];
    const float* wb = (const float*)d_in[5];   // (1,128,128) -> 128x128
    const float* bb = (const float*)d_in[6];   // scalar
    const void*  arcs = d_in[7];

    const int N = in_sizes[0] / HDIM;
    const int E = in_sizes[7] / 2;

    char* ws = (char*)d_ws;
    int* flag = (int*)ws;
    unsigned short* g1 = (unsigned short*)(ws + 256);
    unsigned short* h2 = g1 + (size_t)N * HDIM;

    detect_idx64<<<1, 64, 0, stream>>>((const int*)arcs, flag);

    node_phase<<<512, 512, 0, stream>>>(z, w1, b1, w2, b2, wb, g1, h2, N);

    int eblk = (E + 63) / 64;
    edge_phase<<<eblk, 256, 0, stream>>>(g1, h2, arcs, flag, bb, (float*)d_out, E);
}

// Round 13
// 174.852 us; speedup vs baseline: 1.0909x; 1.0909x over previous
//
#include <hip/hip_runtime.h>
#include <hip/hip_bf16.h>

#define HDIM 128

typedef short bf16x8 __attribute__((ext_vector_type(8)));
typedef short bf16x4 __attribute__((ext_vector_type(4)));
typedef unsigned short u16x8 __attribute__((ext_vector_type(8)));
typedef float f32x4 __attribute__((ext_vector_type(4)));

__device__ __forceinline__ short f2bf(float f) {
    __hip_bfloat16 h = __float2bfloat16(f);
    union { __hip_bfloat16 h; short s; } c; c.h = h; return c.s;
}
__device__ __forceinline__ float bf2f(unsigned short h) {
    union { unsigned u; float f; } c; c.u = ((unsigned)h) << 16; return c.f;
}
__device__ __forceinline__ bf16x8 pack8(float4 a, float4 b) {
    bf16x8 r;
    r[0] = f2bf(a.x); r[1] = f2bf(a.y); r[2] = f2bf(a.z); r[3] = f2bf(a.w);
    r[4] = f2bf(b.x); r[5] = f2bf(b.y); r[6] = f2bf(b.z); r[7] = f2bf(b.w);
    return r;
}

// lgkm-only barrier: orders LDS ops across waves WITHOUT draining vmcnt.
__device__ __forceinline__ void barrier_lds() {
    asm volatile("s_waitcnt lgkmcnt(0)" ::: "memory");
    __builtin_amdgcn_s_barrier();
    __builtin_amdgcn_sched_barrier(0);
}

// ---- phase 1: r8/r11-proven kernel (node ~135us, best measured).
// Persistent, operand-swapped (weights = in-register A fragments), 32-node
// tiles, 1-barrier software pipeline with register z-prefetch one iter ahead.
// Staging bijection: 16 consecutive lanes cover one 512B z-row contiguously
// (16 sectors/wave-load) — do NOT replace with fragment-linear bijection
// (r12: strided rows -> 64 sectors/load -> +16us on the prefetch path).
__global__ __launch_bounds__(512, 4)
void node_phase(const float* __restrict__ z,
                const float* __restrict__ w1, const float* __restrict__ b1,
                const float* __restrict__ w2, const float* __restrict__ b2,
                const float* __restrict__ wb,
                unsigned short* __restrict__ g1, unsigned short* __restrict__ h2o,
                int N)
{
    __shared__ short zbb[2][4096];   // 8 KB each side: z tile, bf16, granule-swizzled
    __shared__ short h1x[2][4096];   // h1 exchange
    __shared__ short h2x[2][4096];   // h2 store staging
    __shared__ short g1x[2][4096];   // g1 store staging

    const int t = threadIdx.x;
    const int lane = t & 63, wid = t >> 6;
    const int l15 = lane & 15, kgrp = lane >> 4;
    const int feat = wid * 16 + l15;

    // persistent weight A-fragments (each matrix read exactly once per block)
    bf16x8 w1f[4], w2f[4], wbf[4];
    {
        const float* w1r = w1 + (size_t)feat * HDIM;
        const float* w2r = w2 + (size_t)feat * HDIM;
#pragma unroll
        for (int kt = 0; kt < 4; ++kt) {
            int k0 = kt * 32 + kgrp * 8;
            w1f[kt] = pack8(*(const float4*)(w1r + k0), *(const float4*)(w1r + k0 + 4));
            w2f[kt] = pack8(*(const float4*)(w2r + k0), *(const float4*)(w2r + k0 + 4));
            bf16x8 r;  // A[i][k=n] = wb[n][feat] column gather (once per block)
#pragma unroll
            for (int i = 0; i < 8; ++i) r[i] = f2bf(wb[(size_t)(k0 + i) * HDIM + feat]);
            wbf[kt] = r;
        }
    }
    f32x4 bias1, bias2;
#pragma unroll
    for (int r = 0; r < 4; ++r) {
        bias1[r] = b1[wid * 16 + kgrp * 4 + r];
        bias2[r] = b2[wid * 16 + kgrp * 4 + r];
    }

    // z/store lane decomposition: thread t owns granule (row=t>>4, pos=t&15);
    // LDS address is LINEAR t*16B (conflict-free); swizzle lives on the SOURCE.
    const int srow = t >> 4;              // 0..31
    const int sp   = t & 15;
    const int sg   = sp ^ (srow & 7);     // pos p holds data granule p^(row&7)

    const int ntiles = (N + 31) >> 5;
    const int myTiles = (ntiles > (int)blockIdx.x)
                      ? ((ntiles - 1 - (int)blockIdx.x) / (int)gridDim.x + 1) : 0;
    const int nit = myTiles + 2;
    const int ng = wid * 2 + (kgrp >> 1);   // D-store granule index

    // prologue: stage tile T_0 into zbb[0]
    if (myTiles > 0) {
        int row = (int)blockIdx.x * 32 + srow;
        int rc = row < N ? row : N - 1;
        const float* src = z + (size_t)rc * HDIM + sg * 8;
        *(bf16x8*)&zbb[0][t * 8] = pack8(*(const float4*)src, *(const float4*)(src + 4));
    }
    __syncthreads();

    for (int i = 0; i < nit; ++i) {
        const int cur = i & 1, prv = cur ^ 1;
        const int tvA = (int)blockIdx.x + i * (int)gridDim.x;
        const bool vA = (i < myTiles);
        const bool vB = (i >= 1) && (i - 1 < myTiles);
        const bool vG = (i >= 2) && (i - 2 < myTiles);
        const bool vP = (i + 1 < myTiles);

        // 1. issue z loads for T_{i+1} (consumed at step 6 -> full iter of cover)
        float4 zn0, zn1;
        if (vP) {
            int row = (tvA + (int)gridDim.x) * 32 + srow;
            int rc = row < N ? row : N - 1;
            const float* src = z + (size_t)rc * HDIM + sg * 8;
            zn0 = *(const float4*)src;
            zn1 = *(const float4*)(src + 4);
        }
        // 2. g1 store for T_{i-2} (16B coalesced: 16 lanes cover a 256B row)
        if (vG) {
            int row = (tvA - 2 * (int)gridDim.x) * 32 + srow;
            u16x8 vv = *(const u16x8*)&g1x[prv][srow * 128 + sp * 8];
            if (row < N) *(u16x8*)&g1[(size_t)row * HDIM + (sp ^ (srow & 7)) * 8] = vv;
        }
        // 3. h2 store for T_{i-1}
        if (vB) {
            int row = (tvA - (int)gridDim.x) * 32 + srow;
            u16x8 vv = *(const u16x8*)&h2x[prv][srow * 128 + sp * 8];
            if (row < N) *(u16x8*)&h2o[(size_t)row * HDIM + (sp ^ (srow & 7)) * 8] = vv;
        }
        // 4. phase A: h1,h2 for T_i from zbb[cur]
        if (vA) {
#pragma unroll
            for (int gp = 0; gp < 2; ++gp) {
                const int m = gp * 16 + l15;
                bf16x8 zf[4];
#pragma unroll
                for (int kt = 0; kt < 4; ++kt) {
                    int pos = (kt * 4 + kgrp) ^ (m & 7);
                    zf[kt] = *(const bf16x8*)&zbb[cur][m * 128 + pos * 8];
                }
                f32x4 a1 = bias1, a3 = bias2;
#pragma unroll
                for (int kt = 0; kt < 4; ++kt) {
                    a1 = __builtin_amdgcn_mfma_f32_16x16x32_bf16(w1f[kt], zf[kt], a1, 0, 0, 0);
                    a3 = __builtin_amdgcn_mfma_f32_16x16x32_bf16(w2f[kt], zf[kt], a3, 0, 0, 0);
                }
                const int sidx = m * 128 + ((ng ^ (m & 7)) << 3) + ((kgrp & 1) << 2);
                bf16x4 h1v, h2v;
#pragma unroll
                for (int r = 0; r < 4; ++r) {
                    float x1 = a1[r] > 0.f ? a1[r] : 0.f;
                    float x2 = a3[r] > 0.f ? a3[r] : 0.f;
                    h1v[r] = f2bf(x1);
                    h2v[r] = f2bf(x2);
                }
                *(bf16x4*)&h1x[cur][sidx] = h1v;
                *(bf16x4*)&h2x[cur][sidx] = h2v;
            }
        }
        // 5. phase B: g1 for T_{i-1} from h1x[prv]
        if (vB) {
#pragma unroll
            for (int gp = 0; gp < 2; ++gp) {
                const int m = gp * 16 + l15;
                f32x4 ag = (f32x4){0.f, 0.f, 0.f, 0.f};
#pragma unroll
                for (int kt = 0; kt < 4; ++kt) {
                    int pos = (kt * 4 + kgrp) ^ (m & 7);
                    bf16x8 bf = *(const bf16x8*)&h1x[prv][m * 128 + pos * 8];
                    ag = __builtin_amdgcn_mfma_f32_16x16x32_bf16(wbf[kt], bf, ag, 0, 0, 0);
                }
                const int sidx = m * 128 + ((ng ^ (m & 7)) << 3) + ((kgrp & 1) << 2);
                bf16x4 gv;
#pragma unroll
                for (int r = 0; r < 4; ++r) gv[r] = f2bf(ag[r]);
                *(bf16x4*)&g1x[cur][sidx] = gv;
            }
        }
        // 6. write next z tile into zbb[prv] (vmcnt waits only past step-1 loads)
        if (vP) {
            *(bf16x8*)&zbb[prv][t * 8] = pack8(zn0, zn1);
        }
        // 7. ONE barrier seals zbb[prv], h1x/h2x/g1x[cur] for the next iteration
        barrier_lds();
    }
}

// ---- index dtype detection (parallel): int64 arcs have zero high words ---
__global__ void detect_idx64(const int* __restrict__ arcs, int* __restrict__ flag)
{
    int v = arcs[2 * threadIdx.x + 1];
    unsigned long long any = __ballot(v != 0);
    if (threadIdx.x == 0) *flag = (any == 0ull) ? 1 : 0;
}

// ---- phase 2: score[e] = dot(g1[u], h2[v]) + bb -------------------------
// 4 edges per 16-lane group: 8 independent 16B gathers in flight per thread.
__global__ __launch_bounds__(256, 8)
void edge_phase(const unsigned short* __restrict__ g1,
                const unsigned short* __restrict__ h2,
                const void* __restrict__ arcs,
                const int* __restrict__ flag,
                const float* __restrict__ bb,
                float* __restrict__ out, int E)
{
    const int t = threadIdx.x;
    const int sub = t & 15;
    const int grp = t >> 4;              // 16 groups/block, 4 edges each
    const bool is64 = (*flag != 0);
    const float bias = bb[0];

    for (int base = (int)blockIdx.x * 64; base < E; base += (int)gridDim.x * 64) {
        const int e0 = base + grp * 4;
        long long u[4], v[4];
#pragma unroll
        for (int j = 0; j < 4; ++j) {
            int ec = (e0 + j) < E ? (e0 + j) : (E - 1);
            if (is64) {
                const long long* a = (const long long*)arcs;
                u[j] = a[2 * (size_t)ec]; v[j] = a[2 * (size_t)ec + 1];
            } else {
                const int* a = (const int*)arcs;
                u[j] = a[2 * (size_t)ec]; v[j] = a[2 * (size_t)ec + 1];
            }
        }
        u16x8 av[4], bv[4];
#pragma unroll
        for (int j = 0; j < 4; ++j) {
            av[j] = *(const u16x8*)(g1 + (size_t)u[j] * HDIM + sub * 8);
            bv[j] = *(const u16x8*)(h2 + (size_t)v[j] * HDIM + sub * 8);
        }
#pragma unroll
        for (int j = 0; j < 4; ++j) {
            float s = 0.f;
#pragma unroll
            for (int i = 0; i < 8; ++i) s += bf2f(av[j][i]) * bf2f(bv[j][i]);
            s += __shfl_xor(s, 8, 16);
            s += __shfl_xor(s, 4, 16);
            s += __shfl_xor(s, 2, 16);
            s += __shfl_xor(s, 1, 16);
            if (sub == 0 && (e0 + j) < E) out[e0 + j] = s + bias;
        }
    }
}

extern "C" void kernel_launch(void* const* d_in, const int* in_sizes, int n_in,
                              void* d_out, int out_size, void* d_ws, size_t ws_size,
                              hipStream_t stream)
{
    const float* z  = (const float*)d_in[0];
    const float* w1 = (const float*)d_in[1];
    const float* b1 = (const float*)d_in[2];
    const float* w2 = (const float*)d_in[3];
    const float* b2 = (const float*)d_in[4];
    const float* wb = (const float*)d_in[5];   // (1,128,128) -> 128x128
    const float* bb = (const float*)d_in[6];   // scalar
    const void*  arcs = d_in[7];

    const int N = in_sizes[0] / HDIM;
    const int E = in_sizes[7] / 2;

    char* ws = (char*)d_ws;
    int* flag = (int*)ws;
    unsigned short* g1 = (unsigned short*)(ws + 256);
    unsigned short* h2 = g1 + (size_t)N * HDIM;

    detect_idx64<<<1, 64, 0, stream>>>((const int*)arcs, flag);

    node_phase<<<512, 512, 0, stream>>>(z, w1, b1, w2, b2, wb, g1, h2, N);

    int eblk = (E + 63) / 64;
    edge_phase<<<eblk, 256, 0, stream>>>(g1, h2, arcs, flag, bb, (float*)d_out, E);
}

// Round 14
// 172.162 us; speedup vs baseline: 1.1080x; 1.0156x over previous
//
#include <hip/hip_runtime.h>
#include <hip/hip_bf16.h>

#define HDIM 128

typedef short bf16x8 __attribute__((ext_vector_type(8)));
typedef short bf16x4 __attribute__((ext_vector_type(4)));
typedef unsigned short u16x8 __attribute__((ext_vector_type(8)));
typedef float f32x4 __attribute__((ext_vector_type(4)));

__device__ __forceinline__ short f2bf(float f) {
    __hip_bfloat16 h = __float2bfloat16(f);
    union { __hip_bfloat16 h; short s; } c; c.h = h; return c.s;
}
__device__ __forceinline__ float bf2f(unsigned short h) {
    union { unsigned u; float f; } c; c.u = ((unsigned)h) << 16; return c.f;
}
__device__ __forceinline__ bf16x8 pack8(float4 a, float4 b) {
    bf16x8 r;
    r[0] = f2bf(a.x); r[1] = f2bf(a.y); r[2] = f2bf(a.z); r[3] = f2bf(a.w);
    r[4] = f2bf(b.x); r[5] = f2bf(b.y); r[6] = f2bf(b.z); r[7] = f2bf(b.w);
    return r;
}

// lgkm-only barrier: orders LDS ops across waves WITHOUT draining vmcnt.
__device__ __forceinline__ void barrier_lds() {
    asm volatile("s_waitcnt lgkmcnt(0)" ::: "memory");
    __builtin_amdgcn_s_barrier();
    __builtin_amdgcn_sched_barrier(0);
}

// ---- phase 1: r8/r11-proven kernel (node ~135us, best measured; verbatim).
// Persistent, operand-swapped (weights = in-register A fragments), 32-node
// tiles, 1-barrier software pipeline with register z-prefetch one iter ahead.
// Staging bijection: 16 consecutive lanes cover one 512B z-row contiguously
// (16 sectors/wave-load) — do NOT replace with fragment-linear bijection
// (r12: strided rows -> 64 sectors/load -> +16us on the prefetch path).
__global__ __launch_bounds__(512, 4)
void node_phase(const float* __restrict__ z,
                const float* __restrict__ w1, const float* __restrict__ b1,
                const float* __restrict__ w2, const float* __restrict__ b2,
                const float* __restrict__ wb,
                unsigned short* __restrict__ g1, unsigned short* __restrict__ h2o,
                int N)
{
    __shared__ short zbb[2][4096];   // 8 KB each side: z tile, bf16, granule-swizzled
    __shared__ short h1x[2][4096];   // h1 exchange
    __shared__ short h2x[2][4096];   // h2 store staging
    __shared__ short g1x[2][4096];   // g1 store staging

    const int t = threadIdx.x;
    const int lane = t & 63, wid = t >> 6;
    const int l15 = lane & 15, kgrp = lane >> 4;
    const int feat = wid * 16 + l15;

    // persistent weight A-fragments (each matrix read exactly once per block)
    bf16x8 w1f[4], w2f[4], wbf[4];
    {
        const float* w1r = w1 + (size_t)feat * HDIM;
        const float* w2r = w2 + (size_t)feat * HDIM;
#pragma unroll
        for (int kt = 0; kt < 4; ++kt) {
            int k0 = kt * 32 + kgrp * 8;
            w1f[kt] = pack8(*(const float4*)(w1r + k0), *(const float4*)(w1r + k0 + 4));
            w2f[kt] = pack8(*(const float4*)(w2r + k0), *(const float4*)(w2r + k0 + 4));
            bf16x8 r;  // A[i][k=n] = wb[n][feat] column gather (once per block)
#pragma unroll
            for (int i = 0; i < 8; ++i) r[i] = f2bf(wb[(size_t)(k0 + i) * HDIM + feat]);
            wbf[kt] = r;
        }
    }
    f32x4 bias1, bias2;
#pragma unroll
    for (int r = 0; r < 4; ++r) {
        bias1[r] = b1[wid * 16 + kgrp * 4 + r];
        bias2[r] = b2[wid * 16 + kgrp * 4 + r];
    }

    // z/store lane decomposition: thread t owns granule (row=t>>4, pos=t&15);
    // LDS address is LINEAR t*16B (conflict-free); swizzle lives on the SOURCE.
    const int srow = t >> 4;              // 0..31
    const int sp   = t & 15;
    const int sg   = sp ^ (srow & 7);     // pos p holds data granule p^(row&7)

    const int ntiles = (N + 31) >> 5;
    const int myTiles = (ntiles > (int)blockIdx.x)
                      ? ((ntiles - 1 - (int)blockIdx.x) / (int)gridDim.x + 1) : 0;
    const int nit = myTiles + 2;
    const int ng = wid * 2 + (kgrp >> 1);   // D-store granule index

    // prologue: stage tile T_0 into zbb[0]
    if (myTiles > 0) {
        int row = (int)blockIdx.x * 32 + srow;
        int rc = row < N ? row : N - 1;
        const float* src = z + (size_t)rc * HDIM + sg * 8;
        *(bf16x8*)&zbb[0][t * 8] = pack8(*(const float4*)src, *(const float4*)(src + 4));
    }
    __syncthreads();

    for (int i = 0; i < nit; ++i) {
        const int cur = i & 1, prv = cur ^ 1;
        const int tvA = (int)blockIdx.x + i * (int)gridDim.x;
        const bool vA = (i < myTiles);
        const bool vB = (i >= 1) && (i - 1 < myTiles);
        const bool vG = (i >= 2) && (i - 2 < myTiles);
        const bool vP = (i + 1 < myTiles);

        // 1. issue z loads for T_{i+1} (consumed at step 6 -> full iter of cover)
        float4 zn0, zn1;
        if (vP) {
            int row = (tvA + (int)gridDim.x) * 32 + srow;
            int rc = row < N ? row : N - 1;
            const float* src = z + (size_t)rc * HDIM + sg * 8;
            zn0 = *(const float4*)src;
            zn1 = *(const float4*)(src + 4);
        }
        // 2. g1 store for T_{i-2} (16B coalesced: 16 lanes cover a 256B row)
        if (vG) {
            int row = (tvA - 2 * (int)gridDim.x) * 32 + srow;
            u16x8 vv = *(const u16x8*)&g1x[prv][srow * 128 + sp * 8];
            if (row < N) *(u16x8*)&g1[(size_t)row * HDIM + (sp ^ (srow & 7)) * 8] = vv;
        }
        // 3. h2 store for T_{i-1}
        if (vB) {
            int row = (tvA - (int)gridDim.x) * 32 + srow;
            u16x8 vv = *(const u16x8*)&h2x[prv][srow * 128 + sp * 8];
            if (row < N) *(u16x8*)&h2o[(size_t)row * HDIM + (sp ^ (srow & 7)) * 8] = vv;
        }
        // 4. phase A: h1,h2 for T_i from zbb[cur]
        if (vA) {
#pragma unroll
            for (int gp = 0; gp < 2; ++gp) {
                const int m = gp * 16 + l15;
                bf16x8 zf[4];
#pragma unroll
                for (int kt = 0; kt < 4; ++kt) {
                    int pos = (kt * 4 + kgrp) ^ (m & 7);
                    zf[kt] = *(const bf16x8*)&zbb[cur][m * 128 + pos * 8];
                }
                f32x4 a1 = bias1, a3 = bias2;
#pragma unroll
                for (int kt = 0; kt < 4; ++kt) {
                    a1 = __builtin_amdgcn_mfma_f32_16x16x32_bf16(w1f[kt], zf[kt], a1, 0, 0, 0);
                    a3 = __builtin_amdgcn_mfma_f32_16x16x32_bf16(w2f[kt], zf[kt], a3, 0, 0, 0);
                }
                const int sidx = m * 128 + ((ng ^ (m & 7)) << 3) + ((kgrp & 1) << 2);
                bf16x4 h1v, h2v;
#pragma unroll
                for (int r = 0; r < 4; ++r) {
                    float x1 = a1[r] > 0.f ? a1[r] : 0.f;
                    float x2 = a3[r] > 0.f ? a3[r] : 0.f;
                    h1v[r] = f2bf(x1);
                    h2v[r] = f2bf(x2);
                }
                *(bf16x4*)&h1x[cur][sidx] = h1v;
                *(bf16x4*)&h2x[cur][sidx] = h2v;
            }
        }
        // 5. phase B: g1 for T_{i-1} from h1x[prv]
        if (vB) {
#pragma unroll
            for (int gp = 0; gp < 2; ++gp) {
                const int m = gp * 16 + l15;
                f32x4 ag = (f32x4){0.f, 0.f, 0.f, 0.f};
#pragma unroll
                for (int kt = 0; kt < 4; ++kt) {
                    int pos = (kt * 4 + kgrp) ^ (m & 7);
                    bf16x8 bf = *(const bf16x8*)&h1x[prv][m * 128 + pos * 8];
                    ag = __builtin_amdgcn_mfma_f32_16x16x32_bf16(wbf[kt], bf, ag, 0, 0, 0);
                }
                const int sidx = m * 128 + ((ng ^ (m & 7)) << 3) + ((kgrp & 1) << 2);
                bf16x4 gv;
#pragma unroll
                for (int r = 0; r < 4; ++r) gv[r] = f2bf(ag[r]);
                *(bf16x4*)&g1x[cur][sidx] = gv;
            }
        }
        // 6. write next z tile into zbb[prv] (vmcnt waits only past step-1 loads)
        if (vP) {
            *(bf16x8*)&zbb[prv][t * 8] = pack8(zn0, zn1);
        }
        // 7. ONE barrier seals zbb[prv], h1x/h2x/g1x[cur] for the next iteration
        barrier_lds();
    }
}

// ---- phase 2: score[e] = dot(g1[u], h2[v]) + bb -------------------------
// 4 edges per 16-lane group: 8 independent 16B gathers in flight per thread.
// Index dtype detection is INLINE (all 4 waves ballot the same 64 high-words
// -> identical, deterministic conclusion; removes the serialized pre-launch).
__global__ __launch_bounds__(256, 8)
void edge_phase(const unsigned short* __restrict__ g1,
                const unsigned short* __restrict__ h2,
                const void* __restrict__ arcs,
                const float* __restrict__ bb,
                float* __restrict__ out, int E)
{
    const int t = threadIdx.x;
    const int sub = t & 15;
    const int grp = t >> 4;              // 16 groups/block, 4 edges each

    // inline int64-vs-int32 detection: under int64, high words are all zero
    int hw = ((const int*)arcs)[2 * (t & 63) + 1];
    const bool is64 = (__ballot(hw != 0) == 0ull);
    const float bias = bb[0];

    for (int base = (int)blockIdx.x * 64; base < E; base += (int)gridDim.x * 64) {
        const int e0 = base + grp * 4;
        long long u[4], v[4];
#pragma unroll
        for (int j = 0; j < 4; ++j) {
            int ec = (e0 + j) < E ? (e0 + j) : (E - 1);
            if (is64) {
                const long long* a = (const long long*)arcs;
                u[j] = a[2 * (size_t)ec]; v[j] = a[2 * (size_t)ec + 1];
            } else {
                const int* a = (const int*)arcs;
                u[j] = a[2 * (size_t)ec]; v[j] = a[2 * (size_t)ec + 1];
            }
        }
        u16x8 av[4], bv[4];
#pragma unroll
        for (int j = 0; j < 4; ++j) {
            av[j] = *(const u16x8*)(g1 + (size_t)u[j] * HDIM + sub * 8);
            bv[j] = *(const u16x8*)(h2 + (size_t)v[j] * HDIM + sub * 8);
        }
#pragma unroll
        for (int j = 0; j < 4; ++j) {
            float s = 0.f;
#pragma unroll
            for (int i = 0; i < 8; ++i) s += bf2f(av[j][i]) * bf2f(bv[j][i]);
            s += __shfl_xor(s, 8, 16);
            s += __shfl_xor(s, 4, 16);
            s += __shfl_xor(s, 2, 16);
            s += __shfl_xor(s, 1, 16);
            if (sub == 0 && (e0 + j) < E) out[e0 + j] = s + bias;
        }
    }
}

extern "C" void kernel_launch(void* const* d_in, const int* in_sizes, int n_in,
                              void* d_out, int out_size, void* d_ws, size_t ws_size,
                              hipStream_t stream)
{
    const float* z  = (const float*)d_in[0];
    const float* w1 = (const float*)d_in[1];
    const float* b1 = (const float*)d_in[2];
    const float* w2 = (const float*)d_in[3];
    const float* b2 = (const float*)d_in[4];
    const float* wb = (const float*)d_in[5];   // (1,128,128) -> 128x128
    const float* bb = (const float*)d_in[6];   // scalar
    const void*  arcs = d_in[7];

    const int N = in_sizes[0] / HDIM;
    const int E = in_sizes[7] / 2;

    char* ws = (char*)d_ws;
    unsigned short* g1 = (unsigned short*)(ws + 256);
    unsigned short* h2 = g1 + (size_t)N * HDIM;

    node_phase<<<512, 512, 0, stream>>>(z, w1, b1, w2, b2, wb, g1, h2, N);

    int eblk = (E + 63) / 64;
    edge_phase<<<eblk, 256, 0, stream>>>(g1, h2, arcs, bb, (float*)d_out, E);
}